// Round 6
// baseline (327.021 us; speedup 1.0000x reference)
//
#include <hip/hip_runtime.h>
#include <hip/hip_bf16.h>

#define T_SEQ 2048
#define DMODEL 2048
#define NB 2
#define NH 16
#define HD 128
#define BK 64

typedef __attribute__((ext_vector_type(8))) short short8;
typedef __attribute__((ext_vector_type(4))) float f32x4;
typedef __attribute__((ext_vector_type(16))) float f32x16;
typedef unsigned short ushort_t;

__device__ inline ushort_t f2bf(float f) {
  union { float f; unsigned u; } v; v.f = f;
  unsigned r = v.u + 0x7fffu + ((v.u >> 16) & 1u);
  return (ushort_t)(r >> 16);
}
__device__ inline float bf2f(ushort_t u) {
  union { unsigned u; float f; } v; v.u = ((unsigned)u) << 16;
  return v.f;
}
__device__ inline unsigned pk2(float x, float y) {
  union { __hip_bfloat162 h; unsigned u; } c;
  c.h = __float22bfloat162_rn(float2{x, y});
  return c.u;
}
__device__ inline float fexp2(float x) {
  float r;
  asm("v_exp_f32 %0, %1" : "=v"(r) : "v"(x));
  return r;
}

__device__ inline void gload16(const void* g, void* l) {
  __builtin_amdgcn_global_load_lds(
      (const __attribute__((address_space(1))) unsigned*)g,
      (__attribute__((address_space(3))) unsigned*)l, 16, 0, 0);
}

// ---------------- fp32 -> bf16 convert, 8 elems/thread ----------------
__global__ void cvt_f32_bf16(const float* __restrict__ src, ushort_t* __restrict__ dst, int n8) {
  int i = blockIdx.x * blockDim.x + threadIdx.x;
  if (i >= n8) return;
  const float4* s = (const float4*)src + (size_t)i * 2;
  float4 a = s[0], b = s[1];
  short8 o;
  o[0] = (short)f2bf(a.x); o[1] = (short)f2bf(a.y);
  o[2] = (short)f2bf(a.z); o[3] = (short)f2bf(a.w);
  o[4] = (short)f2bf(b.x); o[5] = (short)f2bf(b.y);
  o[6] = (short)f2bf(b.z); o[7] = (short)f2bf(b.w);
  *((short8*)dst + i) = o;
}

// ---------------- cos/sin table: trig[t*128 + i*2]=cos, +1=sin --------
__global__ void trig_init(float* __restrict__ trig) {
  int idx = blockIdx.x * blockDim.x + threadIdx.x;  // T*64
  if (idx >= T_SEQ * 64) return;
  int i = idx & 63, t = idx >> 6;
  float inv = __expf(-(float)i * (9.210340371976184f / 64.0f));
  float f = (float)t * inv;
  trig[idx * 2]     = cosf(f);
  trig[idx * 2 + 1] = sinf(f);
}

// ---------------- V transpose: [B][H][T][128] -> [B][H][128][T] -------
__global__ __launch_bounds__(256)
void v_transpose(const ushort_t* __restrict__ v, ushort_t* __restrict__ vt) {
  __shared__ __align__(16) ushort_t L[64][136];
  int bh = blockIdx.y;
  int t0 = blockIdx.x * 64;
  int tid = threadIdx.x;
  int row = tid >> 2, c0 = (tid & 3) * 32;
  const ushort_t* src = v + ((size_t)bh * T_SEQ + t0 + row) * HD + c0;
#pragma unroll
  for (int j = 0; j < 4; ++j)
    *(short8*)&L[row][c0 + j * 8] = *(const short8*)(src + j * 8);
  __syncthreads();
  int d = tid >> 1, tc = (tid & 1) * 32;
  union { ushort_t u[32]; short8 v8[4]; } buf;
#pragma unroll
  for (int j = 0; j < 32; ++j) buf.u[j] = L[tc + j][d];
  ushort_t* dst = vt + ((size_t)bh * HD + d) * T_SEQ + t0 + tc;
#pragma unroll
  for (int j = 0; j < 4; ++j) *(short8*)(dst + j * 8) = buf.v8[j];
}

// ============== 256x256 8-phase counted-vmcnt GEMM (bf16, fp32 acc) ===
// C = A[M][K] * Bt[N][K]^T. 512 thr = 8 waves (2M x 4N), per-wave 128x64.
// Iteration = 2 K-tiles: tile 2i -> buf0 (phases 0-3), 2i+1 -> buf1 (4-7).
// Per phase: {ds_read A quadrant (+B at p0/p4) | stage 1 half-tile (2
// gloads) | barrier | lgkmcnt(0) | 16 MFMA | barrier}. vmcnt(4) ONLY at
// end of p3 and p7 (T4 counted waits; 4 newest loads stay in flight).
// Stage slots: p0/p1=A-buf1(u+1), p2/p3=B-buf0(u+2), p4/p5=A-buf0(u+2),
// p6/p7=B-buf1(u+3) — each target freed by a preceding barrier.
template <int EPI>
__global__ __launch_bounds__(512, 2)
void gemm256(const ushort_t* __restrict__ A, const ushort_t* __restrict__ Bt,
             float* __restrict__ C, ushort_t* __restrict__ q_t,
             ushort_t* __restrict__ k_t, ushort_t* __restrict__ v_t,
             const float* __restrict__ trig, int M, int N, int K) {
  __shared__ __align__(16) ushort_t sA[2][256 * 64];  // 64 KiB
  __shared__ __align__(16) ushort_t sB[2][256 * 64];  // 64 KiB
  int tid = threadIdx.x, lane = tid & 63, w = tid >> 6;
  int wm = w >> 2, wn = w & 3;
  int li = lane & 15, lg = lane >> 4;
  // bijective XCD swizzle (grid count % 8 == 0 for both call sites)
  int nwg = gridDim.x * gridDim.y;
  int flat = blockIdx.y * gridDim.x + blockIdx.x;
  int cpx = nwg >> 3;
  int swz = (flat & 7) * cpx + (flat >> 3);
  int bx = swz % gridDim.x, by = swz / gridDim.x;
  int tile_m = by * 256, tile_n = bx * 256;
  const ushort_t* Ag = A + (size_t)tile_m * K;
  const ushort_t* Bg = Bt + (size_t)tile_n * K;

  int srow = w * 16 + (lane >> 3);
  int schunk = ((lane & 7) ^ (lane >> 3)) * 8;

  auto stageA = [&](int half, int kt, int buf) {
#pragma unroll
    for (int i = 0; i < 2; ++i) {
      int row = half * 128 + srow + i * 8;
      gload16(Ag + (size_t)row * K + kt * BK + schunk,
              &sA[buf][half * 8192 + w * 1024 + i * 512]);
    }
  };
  auto stageB = [&](int half, int kt, int buf) {
#pragma unroll
    for (int i = 0; i < 2; ++i) {
      int row = half * 128 + srow + i * 8;
      gload16(Bg + (size_t)row * K + kt * BK + schunk,
              &sB[buf][half * 8192 + w * 1024 + i * 512]);
    }
  };

  f32x4 acc[8][4] = {};
  short8 bfr[4][2];
  const int NITER = K / (2 * BK);

  // prologue: tile0 A+B -> buf0, tile1 B -> buf1 (tile1 A staged at p0/p1)
  stageA(0, 0, 0); stageA(1, 0, 0);
  stageB(0, 0, 0); stageB(1, 0, 0);
  stageB(0, 1, 1); stageB(1, 1, 1);
  asm volatile("s_waitcnt vmcnt(0)" ::: "memory");
  __syncthreads();

  for (int it = 0; it < NITER; ++it) {
    int u = 2 * it;
    bool last = (it == NITER - 1);
#pragma unroll
    for (int p = 0; p < 8; ++p) {
      const int lp = p & 3, buf = p >> 2;
      short8 af[2][2];
#pragma unroll
      for (int mm = 0; mm < 2; ++mm) {
        int row = wm * 128 + (lp * 2 + mm) * 16 + li;
#pragma unroll
        for (int kh = 0; kh < 2; ++kh)
          af[mm][kh] = *(const short8*)&sA[buf][row * 64 + (((kh * 4 + lg) ^ (row & 7)) * 8)];
      }
      if (lp == 0) {
#pragma unroll
        for (int n = 0; n < 4; ++n) {
          int row = wn * 64 + n * 16 + li;
#pragma unroll
          for (int kh = 0; kh < 2; ++kh)
            bfr[n][kh] = *(const short8*)&sB[buf][row * 64 + (((kh * 4 + lg) ^ (row & 7)) * 8)];
        }
      }
      // one half-tile stage per phase
      if (p == 0) stageA(0, u + 1, 1);
      else if (p == 1) stageA(1, u + 1, 1);
      else if (p == 2) { if (!last) stageB(0, u + 2, 0); }
      else if (p == 3) { if (!last) stageB(1, u + 2, 0); }
      else if (p == 4) { if (!last) stageA(0, u + 2, 0); }
      else if (p == 5) { if (!last) stageA(1, u + 2, 0); }
      else if (p == 6) { if (!last) stageB(0, u + 3, 1); }
      else if (p == 7) { if (!last) stageB(1, u + 3, 1); }
      __builtin_amdgcn_s_barrier();
      asm volatile("s_waitcnt lgkmcnt(0)" ::: "memory");
      __builtin_amdgcn_sched_barrier(0);
      __builtin_amdgcn_s_setprio(1);
#pragma unroll
      for (int mm = 0; mm < 2; ++mm)
#pragma unroll
        for (int n = 0; n < 4; ++n)
#pragma unroll
          for (int kh = 0; kh < 2; ++kh)
            acc[lp * 2 + mm][n] = __builtin_amdgcn_mfma_f32_16x16x32_bf16(
                af[mm][kh], bfr[n][kh], acc[lp * 2 + mm][n], 0, 0, 0);
      __builtin_amdgcn_s_setprio(0);
      if (p == 3) {
        if (last) asm volatile("s_waitcnt vmcnt(0)" ::: "memory");
        else      asm volatile("s_waitcnt vmcnt(4)" ::: "memory");
      } else if (p == 7) {
        if (!last) asm volatile("s_waitcnt vmcnt(4)" ::: "memory");
      }
      __builtin_amdgcn_s_barrier();
    }
  }

  if (EPI == 0) {
#pragma unroll
    for (int m = 0; m < 8; ++m) {
      int trow = tile_m + wm * 128 + m * 16 + lg * 4;
#pragma unroll
      for (int n = 0; n < 4; ++n) {
        int col = tile_n + wn * 64 + n * 16 + li;
#pragma unroll
        for (int r = 0; r < 4; ++r)
          C[(size_t)(trow + r) * N + col] = acc[m][n][r];
      }
    }
  } else {
    int sec = tile_n >> 11;          // block-uniform (tile inside one section)
    int bq  = tile_m >> 11;
    int t0  = tile_m & 2047;
#pragma unroll
    for (int m = 0; m < 8; ++m) {
      int tl = wm * 128 + m * 16 + lg * 4;
#pragma unroll
      for (int n = 0; n < 4; ++n) {
        int nn = (tile_n & 2047) + wn * 64 + n * 16 + li;
        int h = nn >> 7, d = nn & 127;
        if (sec < 2) {
          ushort_t* base = ((sec == 0) ? q_t : k_t) + ((size_t)(bq * NH + h)) * T_SEQ * HD;
          int fi2 = (d >> 1) * 2;
#pragma unroll
          for (int r = 0; r < 4; ++r) {
            int t = t0 + tl + r;
            float val = acc[m][n][r];
            float par = __shfl_xor(val, 1);
            const float* tp = trig + t * 128 + fi2;
            float c = tp[0], s = tp[1];
            float outv = (li & 1) ? (par * s + val * c) : (val * c - par * s);
            base[(size_t)t * HD + d] = f2bf(outv);
          }
        } else {
          ushort_t* base = v_t + ((size_t)(bq * NH + h)) * T_SEQ * HD;
#pragma unroll
          for (int r = 0; r < 4; ++r)
            base[(size_t)(t0 + tl + r) * HD + d] = f2bf(acc[m][n][r]);
        }
      }
    }
  }
}

// ---------------- Flash attention (causal), swapped-QK 32x32 ----------
__global__ __launch_bounds__(256, 2)
void flash_attn(const ushort_t* __restrict__ Q, const ushort_t* __restrict__ Kg,
                const ushort_t* __restrict__ Vt, ushort_t* __restrict__ Y) {
  __shared__ __align__(16) ushort_t ldsK[2 * 64 * 128];   // 32KB, 2 buf
  __shared__ __align__(16) ushort_t ldsV[2 * 128 * 64];   // 32KB, 2 buf
  int tid = threadIdx.x, lane = tid & 63, w = tid >> 6;
  int hi = lane >> 5, l31 = lane & 31;
  int qi = (blockIdx.y & 16) ? (15 - (int)blockIdx.x) : (int)blockIdx.x;
  int bh = blockIdx.y;
  int b = bh >> 4, h = bh & 15;
  int q0 = qi * 128;
  const ushort_t* Qp = Q + (size_t)bh * T_SEQ * HD;
  const ushort_t* Kp = Kg + (size_t)bh * T_SEQ * HD;
  const ushort_t* Vp = Vt + (size_t)bh * HD * T_SEQ;

  int qg = q0 + w * 32 + l31;
  int qmaxw = q0 + w * 32 + 31;

  auto stage = [&](int kv0, int bsel) {
    ushort_t* Kb = ldsK + bsel * 8192;
    ushort_t* Vb = ldsV + bsel * 8192;
#pragma unroll
    for (int p = 0; p < 4; ++p) {
      int c = p * 256 + w * 64 + lane;
      {
        int row = c >> 4, cc = c & 15;
        int sc = cc ^ (row & 15);
        gload16(Kp + (size_t)(kv0 + row) * HD + sc * 8, Kb + (p * 256 + w * 64) * 8);
      }
      {
        int d = c >> 3, cc = c & 7;
        int sc = cc ^ (d & 7);
        gload16(Vp + (size_t)d * T_SEQ + kv0 + sc * 8, Vb + (p * 256 + w * 64) * 8);
      }
    }
  };

  short8 qf[8];
#pragma unroll
  for (int ds = 0; ds < 8; ++ds)
    qf[ds] = *(const short8*)(Qp + (size_t)qg * HD + ds * 16 + hi * 8);

  f32x16 o[4] = {};
  float mu = -1e30f, l = 0.f;
  const float SIG = 0.12751879523209784f;  // (1/sqrt(128)) * log2(e)

  int nkt = 2 * qi + 2;
  stage(0, 0);
  __syncthreads();
  int cur = 0;
  for (int kt = 0; kt < nkt; ++kt) {
    int kv0 = kt * 64;
    if (kt + 1 < nkt) stage((kt + 1) * 64, cur ^ 1);
    if (kv0 <= qmaxw) {
      const ushort_t* Kb = ldsK + cur * 8192;
      const ushort_t* Vb = ldsV + cur * 8192;
      f32x16 sa = {}, sb = {};
      __builtin_amdgcn_s_setprio(1);
#pragma unroll
      for (int ds = 0; ds < 8; ++ds) {
        int cc = ds * 2 + hi;
        short8 k0 = *(const short8*)&Kb[l31 * 128 + ((cc ^ (l31 & 15)) * 8)];
        short8 k1 = *(const short8*)&Kb[(32 + l31) * 128 + ((cc ^ (l31 & 15)) * 8)];
        sa = __builtin_amdgcn_mfma_f32_32x32x16_bf16(k0, qf[ds], sa, 0, 0, 0);
        sb = __builtin_amdgcn_mfma_f32_32x32x16_bf16(k1, qf[ds], sb, 0, 0, 0);
      }
      __builtin_amdgcn_s_setprio(0);
      float p[32];
#pragma unroll
      for (int r = 0; r < 16; ++r) { p[r] = sa[r] * SIG; p[16 + r] = sb[r] * SIG; }
      if (kv0 + 63 > q0 + w * 32) {
#pragma unroll
        for (int r = 0; r < 16; ++r) {
          int loc = (r & 3) + 8 * (r >> 2) + 4 * hi;
          if (kv0 + loc > qg)      p[r]      = -3e38f;
          if (kv0 + 32 + loc > qg) p[16 + r] = -3e38f;
        }
      }
      float tm[16];
#pragma unroll
      for (int i = 0; i < 16; ++i) tm[i] = fmaxf(p[i], p[i + 16]);
#pragma unroll
      for (int st = 8; st >= 1; st >>= 1)
#pragma unroll
        for (int i = 0; i < 8; ++i)
          if (i < st) tm[i] = fmaxf(tm[i], tm[i + st]);
      float pmax = fmaxf(tm[0], __shfl_xor(tm[0], 32));
      bool resc = !__all(pmax <= mu + 11.0f);
      if (resc) {
        float munew = fmaxf(mu, pmax);
        float alpha = fexp2(mu - munew);
        mu = munew;
        l *= alpha;
#pragma unroll
        for (int dsub = 0; dsub < 4; ++dsub)
#pragma unroll
          for (int r = 0; r < 16; ++r) o[dsub][r] *= alpha;
      }
#pragma unroll
      for (int i = 0; i < 32; ++i) p[i] = fexp2(p[i] - mu);
      float ts[16];
#pragma unroll
      for (int i = 0; i < 16; ++i) ts[i] = p[i] + p[i + 16];
#pragma unroll
      for (int st = 8; st >= 1; st >>= 1)
#pragma unroll
        for (int i = 0; i < 8; ++i)
          if (i < st) ts[i] += ts[i + st];
      l += ts[0] + __shfl_xor(ts[0], 32);
      __builtin_amdgcn_s_setprio(1);
#pragma unroll
      for (int s = 0; s < 4; ++s) {
        int rb = (s >> 1) * 16 + (s & 1) * 8;
        unsigned a0 = pk2(p[rb + 0], p[rb + 1]);
        unsigned a1 = pk2(p[rb + 2], p[rb + 3]);
        unsigned a2 = pk2(p[rb + 4], p[rb + 5]);
        unsigned a3 = pk2(p[rb + 6], p[rb + 7]);
        unsigned sa0 = (unsigned)__shfl_xor((int)a0, 32);
        unsigned sa1 = (unsigned)__shfl_xor((int)a1, 32);
        unsigned sa2 = (unsigned)__shfl_xor((int)a2, 32);
        unsigned sa3 = (unsigned)__shfl_xor((int)a3, 32);
        union { unsigned u[4]; short8 s8; } pf;
        pf.u[0] = hi ? sa2 : a0;
        pf.u[1] = hi ? sa3 : a1;
        pf.u[2] = hi ? a2 : sa0;
        pf.u[3] = hi ? a3 : sa1;
#pragma unroll
        for (int dsub = 0; dsub < 4; ++dsub) {
          int row = dsub * 32 + l31;
          short8 vf = *(const short8*)&Vb[row * 64 + (((2 * s + hi) ^ (row & 7)) * 8)];
          o[dsub] = __builtin_amdgcn_mfma_f32_32x32x16_bf16(vf, pf.s8, o[dsub], 0, 0, 0);
        }
      }
      __builtin_amdgcn_s_setprio(0);
    }
    __syncthreads();
    cur ^= 1;
  }
  float invl = 1.f / l;
#pragma unroll
  for (int dsub = 0; dsub < 4; ++dsub)
#pragma unroll
    for (int r = 0; r < 16; ++r) o[dsub][r] *= invl;
#pragma unroll
  for (int dsub = 0; dsub < 4; ++dsub)
#pragma unroll
    for (int r = 0; r < 16; r += 2) {
      int d0 = dsub * 32 + (r & 3) + 8 * (r >> 2) + 4 * hi;
      unsigned u = pk2(o[dsub][r], o[dsub][r + 1]);
      *(unsigned*)&ldsK[w * 4096 + l31 * 128 + (((d0 >> 3) ^ (l31 & 15)) * 8) + (d0 & 7)] = u;
    }
  __syncthreads();
#pragma unroll
  for (int rep = 0; rep < 8; ++rep) {
    int idx = rep * 256 + tid;
    int qg2 = idx >> 4, c = idx & 15;
    int wv2 = qg2 >> 5, ql = qg2 & 31;
    short8 val = *(const short8*)&ldsK[wv2 * 4096 + ql * 128 + ((c ^ (ql & 15)) * 8)];
    *(short8*)(Y + ((size_t)(b * T_SEQ + q0 + qg2)) * DMODEL + h * HD + c * 8) = val;
  }
}

extern "C" void kernel_launch(void* const* d_in, const int* in_sizes, int n_in,
                              void* d_out, int out_size, void* d_ws, size_t ws_size,
                              hipStream_t stream) {
  const float* x      = (const float*)d_in[0];
  const float* w_attn = (const float*)d_in[1];
  const float* w_proj = (const float*)d_in[2];
  float* out = (float*)d_out;

  char* ws = (char*)d_ws;
  size_t off = 0;
  auto alloc = [&](size_t bytes) -> void* {
    void* p = ws + off;
    off = (off + bytes + 255) & ~(size_t)255;
    return p;
  };
  const size_t MT = (size_t)NB * T_SEQ;          // 4096
  ushort_t* xb   = (ushort_t*)alloc(MT * DMODEL * 2);
  ushort_t* wab  = (ushort_t*)alloc((size_t)3 * DMODEL * DMODEL * 2);
  ushort_t* wpb  = (ushort_t*)alloc((size_t)DMODEL * DMODEL * 2);
  ushort_t* q_t  = (ushort_t*)alloc(MT * DMODEL * 2);
  ushort_t* k_t  = (ushort_t*)alloc(MT * DMODEL * 2);
  ushort_t* v_t  = (ushort_t*)alloc(MT * DMODEL * 2);
  ushort_t* vtb  = (ushort_t*)alloc(MT * DMODEL * 2);
  ushort_t* yb   = (ushort_t*)alloc(MT * DMODEL * 2);
  float*    trig = (float*)alloc((size_t)T_SEQ * 64 * 2 * 4);
  (void)ws_size; (void)n_in; (void)in_sizes; (void)out_size;

  {  // converts
    int n8x = (int)(MT * DMODEL / 8);
    hipLaunchKernelGGL(cvt_f32_bf16, dim3((n8x + 255) / 256), dim3(256), 0, stream, x, xb, n8x);
    int n8a = (int)((size_t)3 * DMODEL * DMODEL / 8);
    hipLaunchKernelGGL(cvt_f32_bf16, dim3((n8a + 255) / 256), dim3(256), 0, stream, w_attn, wab, n8a);
    int n8p = (int)((size_t)DMODEL * DMODEL / 8);
    hipLaunchKernelGGL(cvt_f32_bf16, dim3((n8p + 255) / 256), dim3(256), 0, stream, w_proj, wpb, n8p);
  }
  hipLaunchKernelGGL(trig_init, dim3(T_SEQ * 64 / 256), dim3(256), 0, stream, trig);

  // QKV projection (256^2 8-phase), rope fused for q/k, plain v scatter
  hipLaunchKernelGGL((gemm256<1>), dim3(3 * DMODEL / 256, MT / 256), dim3(512), 0, stream,
                     xb, wab, (float*)nullptr, q_t, k_t, v_t, trig,
                     (int)MT, 3 * DMODEL, DMODEL);

  hipLaunchKernelGGL(v_transpose, dim3(T_SEQ / 64, NB * NH), dim3(256), 0, stream, v_t, vtb);

  hipLaunchKernelGGL(flash_attn, dim3(T_SEQ / 128, NB * NH), dim3(256), 0, stream,
                     q_t, k_t, vtb, yb);

  // output projection (256^2 8-phase)
  hipLaunchKernelGGL((gemm256<0>), dim3(DMODEL / 256, MT / 256), dim3(512), 0, stream,
                     yb, wpb, out, (ushort_t*)nullptr, (ushort_t*)nullptr, (ushort_t*)nullptr,
                     (const float*)nullptr, (int)MT, DMODEL, DMODEL);
}

// Round 7
// 313.431 us; speedup vs baseline: 1.0434x; 1.0434x over previous
//
#include <hip/hip_runtime.h>
#include <hip/hip_bf16.h>

#define T_SEQ 2048
#define DMODEL 2048
#define NB 2
#define NH 16
#define HD 128
#define BK 64

typedef __attribute__((ext_vector_type(8))) short short8;
typedef __attribute__((ext_vector_type(4))) float f32x4;
typedef __attribute__((ext_vector_type(16))) float f32x16;
typedef unsigned short ushort_t;

__device__ inline ushort_t f2bf(float f) {
  union { float f; unsigned u; } v; v.f = f;
  unsigned r = v.u + 0x7fffu + ((v.u >> 16) & 1u);
  return (ushort_t)(r >> 16);
}
__device__ inline float bf2f(ushort_t u) {
  union { unsigned u; float f; } v; v.u = ((unsigned)u) << 16;
  return v.f;
}
__device__ inline unsigned pk2(float x, float y) {
  union { __hip_bfloat162 h; unsigned u; } c;
  c.h = __float22bfloat162_rn(float2{x, y});
  return c.u;
}
__device__ inline float fexp2(float x) {
  float r;
  asm("v_exp_f32 %0, %1" : "=v"(r) : "v"(x));
  return r;
}

__device__ inline void gload16(const void* g, void* l) {
  __builtin_amdgcn_global_load_lds(
      (const __attribute__((address_space(1))) unsigned*)g,
      (__attribute__((address_space(3))) unsigned*)l, 16, 0, 0);
}

// ---------------- fp32 -> bf16 convert, 8 elems/thread ----------------
__global__ void cvt_f32_bf16(const float* __restrict__ src, ushort_t* __restrict__ dst, int n8) {
  int i = blockIdx.x * blockDim.x + threadIdx.x;
  if (i >= n8) return;
  const float4* s = (const float4*)src + (size_t)i * 2;
  float4 a = s[0], b = s[1];
  short8 o;
  o[0] = (short)f2bf(a.x); o[1] = (short)f2bf(a.y);
  o[2] = (short)f2bf(a.z); o[3] = (short)f2bf(a.w);
  o[4] = (short)f2bf(b.x); o[5] = (short)f2bf(b.y);
  o[6] = (short)f2bf(b.z); o[7] = (short)f2bf(b.w);
  *((short8*)dst + i) = o;
}

// ---------------- cos/sin table: trig[t*128 + i*2]=cos, +1=sin --------
__global__ void trig_init(float* __restrict__ trig) {
  int idx = blockIdx.x * blockDim.x + threadIdx.x;  // T*64
  if (idx >= T_SEQ * 64) return;
  int i = idx & 63, t = idx >> 6;
  float inv = __expf(-(float)i * (9.210340371976184f / 64.0f));
  float f = (float)t * inv;
  trig[idx * 2]     = cosf(f);
  trig[idx * 2 + 1] = sinf(f);
}

// ---------------- V transpose: [B][H][T][128] -> [B][H][128][T] -------
__global__ __launch_bounds__(256)
void v_transpose(const ushort_t* __restrict__ v, ushort_t* __restrict__ vt) {
  __shared__ __align__(16) ushort_t L[64][136];
  int bh = blockIdx.y;
  int t0 = blockIdx.x * 64;
  int tid = threadIdx.x;
  int row = tid >> 2, c0 = (tid & 3) * 32;
  const ushort_t* src = v + ((size_t)bh * T_SEQ + t0 + row) * HD + c0;
#pragma unroll
  for (int j = 0; j < 4; ++j)
    *(short8*)&L[row][c0 + j * 8] = *(const short8*)(src + j * 8);
  __syncthreads();
  int d = tid >> 1, tc = (tid & 1) * 32;
  union { ushort_t u[32]; short8 v8[4]; } buf;
#pragma unroll
  for (int j = 0; j < 32; ++j) buf.u[j] = L[tc + j][d];
  ushort_t* dst = vt + ((size_t)bh * HD + d) * T_SEQ + t0 + tc;
#pragma unroll
  for (int j = 0; j < 4; ++j) *(short8*)(dst + j * 8) = buf.v8[j];
}

// ========= 256xTN 8-phase counted-vmcnt GEMM (bf16, fp32 acc) =========
// C = A[M][K] * Bt[N][K]^T. 512 thr = 8 waves (2M x 4N); per-wave 128 x TN/4.
// Iteration = 2 K-tiles (buf0: even tile, buf1: odd). 8 phases/iter, each
// {ds_read A quadrant (+B at p0/p4) | stage | barrier | lgkmcnt(0) | MFMA |
// barrier}; counted vmcnt only at p3/p7 (TN=256: vmcnt(4); TN=128: vmcnt(2)).
// Natural blockIdx order (no XCD swizzle: wide-N grids get B-panel L2
// affinity per XCD for free; swizzle regressed FETCH +77MB in R6).
template <int EPI, int TN>
__global__ __launch_bounds__(512, 2)
void gemm256(const ushort_t* __restrict__ A, const ushort_t* __restrict__ Bt,
             float* __restrict__ C, ushort_t* __restrict__ q_t,
             ushort_t* __restrict__ k_t, ushort_t* __restrict__ v_t,
             const float* __restrict__ trig, int M, int N, int K) {
  constexpr int NF = TN / 64;          // B n-frags per wave
  constexpr int VC = (TN == 256) ? 4 : 2;
  __shared__ __align__(16) ushort_t sA[2][256 * 64];
  __shared__ __align__(16) ushort_t sB[2][TN * 64];
  int tid = threadIdx.x, lane = tid & 63, w = tid >> 6;
  int wm = w >> 2, wn = w & 3;
  int li = lane & 15, lg = lane >> 4;
  int tile_m = blockIdx.y * 256, tile_n = blockIdx.x * TN;
  const ushort_t* Ag = A + (size_t)tile_m * K;
  const ushort_t* Bg = Bt + (size_t)tile_n * K;

  int srow = w * 16 + (lane >> 3);
  int schunk = ((lane & 7) ^ (lane >> 3)) * 8;

  auto stageA = [&](int half, int kt, int buf) {
#pragma unroll
    for (int i = 0; i < 2; ++i) {
      int row = half * 128 + srow + i * 8;
      gload16(Ag + (size_t)row * K + kt * BK + schunk,
              &sA[buf][half * 8192 + w * 1024 + i * 512]);
    }
  };
  auto stageB = [&](int half, int kt, int buf) {
#pragma unroll
    for (int i = 0; i < 2; ++i) {
      int row = half * 128 + srow + i * 8;
      gload16(Bg + (size_t)row * K + kt * BK + schunk,
              &sB[buf][half * 8192 + w * 1024 + i * 512]);
    }
  };

  f32x4 acc[8][NF] = {};
  short8 bfr[NF][2];
  const int NITER = K / (2 * BK);

  // prologue: tile0 A+B -> buf0, tile1 B -> buf1 (tile1 A staged at p0/p1)
  stageA(0, 0, 0); stageA(1, 0, 0);
  stageB(0, 0, 0);
  if (TN == 256) stageB(1, 0, 0);
  stageB(0, 1, 1);
  if (TN == 256) stageB(1, 1, 1);
  asm volatile("s_waitcnt vmcnt(0)" ::: "memory");
  __syncthreads();

  for (int it = 0; it < NITER; ++it) {
    int u = 2 * it;
    bool last = (it == NITER - 1);
#pragma unroll
    for (int p = 0; p < 8; ++p) {
      const int lp = p & 3, buf = p >> 2;
      short8 af[2][2];
#pragma unroll
      for (int mm = 0; mm < 2; ++mm) {
        int row = wm * 128 + (lp * 2 + mm) * 16 + li;
#pragma unroll
        for (int kh = 0; kh < 2; ++kh)
          af[mm][kh] = *(const short8*)&sA[buf][row * 64 + (((kh * 4 + lg) ^ (row & 7)) * 8)];
      }
      if (lp == 0) {
#pragma unroll
        for (int n = 0; n < NF; ++n) {
          int row = wn * (TN / 4) + n * 16 + li;
#pragma unroll
          for (int kh = 0; kh < 2; ++kh)
            bfr[n][kh] = *(const short8*)&sB[buf][row * 64 + (((kh * 4 + lg) ^ (row & 7)) * 8)];
        }
      }
      // one stage slot per phase
      if (TN == 256) {
        if (p == 0) stageA(0, u + 1, 1);
        else if (p == 1) stageA(1, u + 1, 1);
        else if (p == 2) { if (!last) stageB(0, u + 2, 0); }
        else if (p == 3) { if (!last) stageB(1, u + 2, 0); }
        else if (p == 4) { if (!last) stageA(0, u + 2, 0); }
        else if (p == 5) { if (!last) stageA(1, u + 2, 0); }
        else if (p == 6) { if (!last) stageB(0, u + 3, 1); }
        else if (p == 7) { if (!last) stageB(1, u + 3, 1); }
      } else {
        if (p == 0) stageA(0, u + 1, 1);
        else if (p == 1) stageA(1, u + 1, 1);
        else if (p == 2) { if (!last) stageB(0, u + 2, 0); }
        else if (p == 4) { if (!last) stageA(0, u + 2, 0); }
        else if (p == 5) { if (!last) stageA(1, u + 2, 0); }
        else if (p == 6) { if (!last) stageB(0, u + 3, 1); }
      }
      __builtin_amdgcn_s_barrier();
      asm volatile("s_waitcnt lgkmcnt(0)" ::: "memory");
      __builtin_amdgcn_sched_barrier(0);
      __builtin_amdgcn_s_setprio(1);
#pragma unroll
      for (int mm = 0; mm < 2; ++mm)
#pragma unroll
        for (int n = 0; n < NF; ++n)
#pragma unroll
          for (int kh = 0; kh < 2; ++kh)
            acc[lp * 2 + mm][n] = __builtin_amdgcn_mfma_f32_16x16x32_bf16(
                af[mm][kh], bfr[n][kh], acc[lp * 2 + mm][n], 0, 0, 0);
      __builtin_amdgcn_s_setprio(0);
      if (p == 3) {
        if (last) asm volatile("s_waitcnt vmcnt(0)" ::: "memory");
        else      asm volatile("s_waitcnt vmcnt(%0)" :: "i"(VC) : "memory");
      } else if (p == 7) {
        if (!last) asm volatile("s_waitcnt vmcnt(%0)" :: "i"(VC) : "memory");
      }
      __builtin_amdgcn_s_barrier();
    }
  }

  if (EPI == 0) {
#pragma unroll
    for (int m = 0; m < 8; ++m) {
      int trow = tile_m + wm * 128 + m * 16 + lg * 4;
#pragma unroll
      for (int n = 0; n < NF; ++n) {
        int col = tile_n + wn * (TN / 4) + n * 16 + li;
#pragma unroll
        for (int r = 0; r < 4; ++r)
          C[(size_t)(trow + r) * N + col] = acc[m][n][r];
      }
    }
  } else {
    int sec = tile_n >> 11;          // block-uniform (tile inside one section)
    int bq  = tile_m >> 11;
    int t0  = tile_m & 2047;
#pragma unroll
    for (int m = 0; m < 8; ++m) {
      int tl = wm * 128 + m * 16 + lg * 4;
#pragma unroll
      for (int n = 0; n < NF; ++n) {
        int nn = (tile_n & 2047) + wn * (TN / 4) + n * 16 + li;
        int h = nn >> 7, d = nn & 127;
        if (sec < 2) {
          ushort_t* base = ((sec == 0) ? q_t : k_t) + ((size_t)(bq * NH + h)) * T_SEQ * HD;
          int fi2 = (d >> 1) * 2;
#pragma unroll
          for (int r = 0; r < 4; ++r) {
            int t = t0 + tl + r;
            float val = acc[m][n][r];
            float par = __shfl_xor(val, 1);
            const float* tp = trig + t * 128 + fi2;
            float c = tp[0], s = tp[1];
            float outv = (li & 1) ? (par * s + val * c) : (val * c - par * s);
            base[(size_t)t * HD + d] = f2bf(outv);
          }
        } else {
          ushort_t* base = v_t + ((size_t)(bq * NH + h)) * T_SEQ * HD;
#pragma unroll
          for (int r = 0; r < 4; ++r)
            base[(size_t)(t0 + tl + r) * HD + d] = f2bf(acc[m][n][r]);
        }
      }
    }
  }
}

// ---------------- Flash attention (causal), swapped-QK 32x32 ----------
__global__ __launch_bounds__(256, 2)
void flash_attn(const ushort_t* __restrict__ Q, const ushort_t* __restrict__ Kg,
                const ushort_t* __restrict__ Vt, ushort_t* __restrict__ Y) {
  __shared__ __align__(16) ushort_t ldsK[2 * 64 * 128];   // 32KB, 2 buf
  __shared__ __align__(16) ushort_t ldsV[2 * 128 * 64];   // 32KB, 2 buf
  int tid = threadIdx.x, lane = tid & 63, w = tid >> 6;
  int hi = lane >> 5, l31 = lane & 31;
  int qi = (blockIdx.y & 16) ? (15 - (int)blockIdx.x) : (int)blockIdx.x;
  int bh = blockIdx.y;
  int b = bh >> 4, h = bh & 15;
  int q0 = qi * 128;
  const ushort_t* Qp = Q + (size_t)bh * T_SEQ * HD;
  const ushort_t* Kp = Kg + (size_t)bh * T_SEQ * HD;
  const ushort_t* Vp = Vt + (size_t)bh * HD * T_SEQ;

  int qg = q0 + w * 32 + l31;
  int qmaxw = q0 + w * 32 + 31;

  auto stage = [&](int kv0, int bsel) {
    ushort_t* Kb = ldsK + bsel * 8192;
    ushort_t* Vb = ldsV + bsel * 8192;
#pragma unroll
    for (int p = 0; p < 4; ++p) {
      int c = p * 256 + w * 64 + lane;
      {
        int row = c >> 4, cc = c & 15;
        int sc = cc ^ (row & 15);
        gload16(Kp + (size_t)(kv0 + row) * HD + sc * 8, Kb + (p * 256 + w * 64) * 8);
      }
      {
        int d = c >> 3, cc = c & 7;
        int sc = cc ^ (d & 7);
        gload16(Vp + (size_t)d * T_SEQ + kv0 + sc * 8, Vb + (p * 256 + w * 64) * 8);
      }
    }
  };

  short8 qf[8];
#pragma unroll
  for (int ds = 0; ds < 8; ++ds)
    qf[ds] = *(const short8*)(Qp + (size_t)qg * HD + ds * 16 + hi * 8);

  f32x16 o[4] = {};
  float mu = -1e30f, l = 0.f;
  const float SIG = 0.12751879523209784f;  // (1/sqrt(128)) * log2(e)

  int nkt = 2 * qi + 2;
  stage(0, 0);
  __syncthreads();
  int cur = 0;
  for (int kt = 0; kt < nkt; ++kt) {
    int kv0 = kt * 64;
    if (kt + 1 < nkt) stage((kt + 1) * 64, cur ^ 1);
    if (kv0 <= qmaxw) {
      const ushort_t* Kb = ldsK + cur * 8192;
      const ushort_t* Vb = ldsV + cur * 8192;
      f32x16 sa = {}, sb = {};
      __builtin_amdgcn_s_setprio(1);
#pragma unroll
      for (int ds = 0; ds < 8; ++ds) {
        int cc = ds * 2 + hi;
        short8 k0 = *(const short8*)&Kb[l31 * 128 + ((cc ^ (l31 & 15)) * 8)];
        short8 k1 = *(const short8*)&Kb[(32 + l31) * 128 + ((cc ^ (l31 & 15)) * 8)];
        sa = __builtin_amdgcn_mfma_f32_32x32x16_bf16(k0, qf[ds], sa, 0, 0, 0);
        sb = __builtin_amdgcn_mfma_f32_32x32x16_bf16(k1, qf[ds], sb, 0, 0, 0);
      }
      __builtin_amdgcn_s_setprio(0);
      float p[32];
#pragma unroll
      for (int r = 0; r < 16; ++r) { p[r] = sa[r] * SIG; p[16 + r] = sb[r] * SIG; }
      if (kv0 + 63 > q0 + w * 32) {
#pragma unroll
        for (int r = 0; r < 16; ++r) {
          int loc = (r & 3) + 8 * (r >> 2) + 4 * hi;
          if (kv0 + loc > qg)      p[r]      = -3e38f;
          if (kv0 + 32 + loc > qg) p[16 + r] = -3e38f;
        }
      }
      float tm[16];
#pragma unroll
      for (int i = 0; i < 16; ++i) tm[i] = fmaxf(p[i], p[i + 16]);
#pragma unroll
      for (int st = 8; st >= 1; st >>= 1)
#pragma unroll
        for (int i = 0; i < 8; ++i)
          if (i < st) tm[i] = fmaxf(tm[i], tm[i + st]);
      float pmax = fmaxf(tm[0], __shfl_xor(tm[0], 32));
      bool resc = !__all(pmax <= mu + 11.0f);
      if (resc) {
        float munew = fmaxf(mu, pmax);
        float alpha = fexp2(mu - munew);
        mu = munew;
        l *= alpha;
#pragma unroll
        for (int dsub = 0; dsub < 4; ++dsub)
#pragma unroll
          for (int r = 0; r < 16; ++r) o[dsub][r] *= alpha;
      }
#pragma unroll
      for (int i = 0; i < 32; ++i) p[i] = fexp2(p[i] - mu);
      float ts[16];
#pragma unroll
      for (int i = 0; i < 16; ++i) ts[i] = p[i] + p[i + 16];
#pragma unroll
      for (int st = 8; st >= 1; st >>= 1)
#pragma unroll
        for (int i = 0; i < 8; ++i)
          if (i < st) ts[i] += ts[i + st];
      l += ts[0] + __shfl_xor(ts[0], 32);
      __builtin_amdgcn_s_setprio(1);
#pragma unroll
      for (int s = 0; s < 4; ++s) {
        int rb = (s >> 1) * 16 + (s & 1) * 8;
        unsigned a0 = pk2(p[rb + 0], p[rb + 1]);
        unsigned a1 = pk2(p[rb + 2], p[rb + 3]);
        unsigned a2 = pk2(p[rb + 4], p[rb + 5]);
        unsigned a3 = pk2(p[rb + 6], p[rb + 7]);
        unsigned sa0 = (unsigned)__shfl_xor((int)a0, 32);
        unsigned sa1 = (unsigned)__shfl_xor((int)a1, 32);
        unsigned sa2 = (unsigned)__shfl_xor((int)a2, 32);
        unsigned sa3 = (unsigned)__shfl_xor((int)a3, 32);
        union { unsigned u[4]; short8 s8; } pf;
        pf.u[0] = hi ? sa2 : a0;
        pf.u[1] = hi ? sa3 : a1;
        pf.u[2] = hi ? a2 : sa0;
        pf.u[3] = hi ? a3 : sa1;
#pragma unroll
        for (int dsub = 0; dsub < 4; ++dsub) {
          int row = dsub * 32 + l31;
          short8 vf = *(const short8*)&Vb[row * 64 + (((2 * s + hi) ^ (row & 7)) * 8)];
          o[dsub] = __builtin_amdgcn_mfma_f32_32x32x16_bf16(vf, pf.s8, o[dsub], 0, 0, 0);
        }
      }
      __builtin_amdgcn_s_setprio(0);
    }
    __syncthreads();
    cur ^= 1;
  }
  float invl = 1.f / l;
#pragma unroll
  for (int dsub = 0; dsub < 4; ++dsub)
#pragma unroll
    for (int r = 0; r < 16; ++r) o[dsub][r] *= invl;
#pragma unroll
  for (int dsub = 0; dsub < 4; ++dsub)
#pragma unroll
    for (int r = 0; r < 16; r += 2) {
      int d0 = dsub * 32 + (r & 3) + 8 * (r >> 2) + 4 * hi;
      unsigned u = pk2(o[dsub][r], o[dsub][r + 1]);
      *(unsigned*)&ldsK[w * 4096 + l31 * 128 + (((d0 >> 3) ^ (l31 & 15)) * 8) + (d0 & 7)] = u;
    }
  __syncthreads();
#pragma unroll
  for (int rep = 0; rep < 8; ++rep) {
    int idx = rep * 256 + tid;
    int qg2 = idx >> 4, c = idx & 15;
    int wv2 = qg2 >> 5, ql = qg2 & 31;
    short8 val = *(const short8*)&ldsK[wv2 * 4096 + ql * 128 + ((c ^ (ql & 15)) * 8)];
    *(short8*)(Y + ((size_t)(b * T_SEQ + q0 + qg2)) * DMODEL + h * HD + c * 8) = val;
  }
}

extern "C" void kernel_launch(void* const* d_in, const int* in_sizes, int n_in,
                              void* d_out, int out_size, void* d_ws, size_t ws_size,
                              hipStream_t stream) {
  const float* x      = (const float*)d_in[0];
  const float* w_attn = (const float*)d_in[1];
  const float* w_proj = (const float*)d_in[2];
  float* out = (float*)d_out;

  char* ws = (char*)d_ws;
  size_t off = 0;
  auto alloc = [&](size_t bytes) -> void* {
    void* p = ws + off;
    off = (off + bytes + 255) & ~(size_t)255;
    return p;
  };
  const size_t MT = (size_t)NB * T_SEQ;          // 4096
  ushort_t* xb   = (ushort_t*)alloc(MT * DMODEL * 2);
  ushort_t* wab  = (ushort_t*)alloc((size_t)3 * DMODEL * DMODEL * 2);
  ushort_t* wpb  = (ushort_t*)alloc((size_t)DMODEL * DMODEL * 2);
  ushort_t* q_t  = (ushort_t*)alloc(MT * DMODEL * 2);
  ushort_t* k_t  = (ushort_t*)alloc(MT * DMODEL * 2);
  ushort_t* v_t  = (ushort_t*)alloc(MT * DMODEL * 2);
  ushort_t* vtb  = (ushort_t*)alloc(MT * DMODEL * 2);
  ushort_t* yb   = (ushort_t*)alloc(MT * DMODEL * 2);
  float*    trig = (float*)alloc((size_t)T_SEQ * 64 * 2 * 4);
  (void)ws_size; (void)n_in; (void)in_sizes; (void)out_size;

  {  // converts
    int n8x = (int)(MT * DMODEL / 8);
    hipLaunchKernelGGL(cvt_f32_bf16, dim3((n8x + 255) / 256), dim3(256), 0, stream, x, xb, n8x);
    int n8a = (int)((size_t)3 * DMODEL * DMODEL / 8);
    hipLaunchKernelGGL(cvt_f32_bf16, dim3((n8a + 255) / 256), dim3(256), 0, stream, w_attn, wab, n8a);
    int n8p = (int)((size_t)DMODEL * DMODEL / 8);
    hipLaunchKernelGGL(cvt_f32_bf16, dim3((n8p + 255) / 256), dim3(256), 0, stream, w_proj, wpb, n8p);
  }
  hipLaunchKernelGGL(trig_init, dim3(T_SEQ * 64 / 256), dim3(256), 0, stream, trig);

  // QKV projection (256x256 8-phase), rope fused for q/k, plain v scatter
  hipLaunchKernelGGL((gemm256<1, 256>), dim3(3 * DMODEL / 256, MT / 256), dim3(512), 0, stream,
                     xb, wab, (float*)nullptr, q_t, k_t, v_t, trig,
                     (int)MT, 3 * DMODEL, DMODEL);

  hipLaunchKernelGGL(v_transpose, dim3(T_SEQ / 64, NB * NH), dim3(256), 0, stream, v_t, vtb);

  hipLaunchKernelGGL(flash_attn, dim3(T_SEQ / 128, NB * NH), dim3(256), 0, stream,
                     q_t, k_t, vtb, yb);

  // output projection (256x128 tile -> 256 blocks = exact full-GPU fit)
  hipLaunchKernelGGL((gemm256<0, 128>), dim3(DMODEL / 128, MT / 256), dim3(512), 0, stream,
                     yb, wpb, out, (ushort_t*)nullptr, (ushort_t*)nullptr, (ushort_t*)nullptr,
                     (const float*)nullptr, (int)MT, DMODEL, DMODEL);
}

// Round 8
// 309.969 us; speedup vs baseline: 1.0550x; 1.0112x over previous
//
#include <hip/hip_runtime.h>
#include <hip/hip_bf16.h>

#define T_SEQ 2048
#define DMODEL 2048
#define NB 2
#define NH 16
#define HD 128

typedef __attribute__((ext_vector_type(8))) short short8;
typedef __attribute__((ext_vector_type(4))) float f32x4;
typedef __attribute__((ext_vector_type(16))) float f32x16;
typedef unsigned short ushort_t;

__device__ inline ushort_t f2bf(float f) {
  union { float f; unsigned u; } v; v.f = f;
  unsigned r = v.u + 0x7fffu + ((v.u >> 16) & 1u);
  return (ushort_t)(r >> 16);
}
__device__ inline float bf2f(ushort_t u) {
  union { unsigned u; float f; } v; v.u = ((unsigned)u) << 16;
  return v.f;
}
__device__ inline unsigned pk2(float x, float y) {
  union { __hip_bfloat162 h; unsigned u; } c;
  c.h = __float22bfloat162_rn(float2{x, y});
  return c.u;
}
__device__ inline float fexp2(float x) {
  float r;
  asm("v_exp_f32 %0, %1" : "=v"(r) : "v"(x));
  return r;
}

__device__ inline void gload16(const void* g, void* l) {
  __builtin_amdgcn_global_load_lds(
      (const __attribute__((address_space(1))) unsigned*)g,
      (__attribute__((address_space(3))) unsigned*)l, 16, 0, 0);
}

// ---------------- fp32 -> bf16 convert, 8 elems/thread ----------------
__global__ void cvt_f32_bf16(const float* __restrict__ src, ushort_t* __restrict__ dst, int n8) {
  int i = blockIdx.x * blockDim.x + threadIdx.x;
  if (i >= n8) return;
  const float4* s = (const float4*)src + (size_t)i * 2;
  float4 a = s[0], b = s[1];
  short8 o;
  o[0] = (short)f2bf(a.x); o[1] = (short)f2bf(a.y);
  o[2] = (short)f2bf(a.z); o[3] = (short)f2bf(a.w);
  o[4] = (short)f2bf(b.x); o[5] = (short)f2bf(b.y);
  o[6] = (short)f2bf(b.z); o[7] = (short)f2bf(b.w);
  *((short8*)dst + i) = o;
}

// ---------------- cos/sin table: trig[t*128 + i*2]=cos, +1=sin --------
__global__ void trig_init(float* __restrict__ trig) {
  int idx = blockIdx.x * blockDim.x + threadIdx.x;  // T*64
  if (idx >= T_SEQ * 64) return;
  int i = idx & 63, t = idx >> 6;
  float inv = __expf(-(float)i * (9.210340371976184f / 64.0f));
  float f = (float)t * inv;
  trig[idx * 2]     = cosf(f);
  trig[idx * 2 + 1] = sinf(f);
}

// ---------------- V transpose: [B][H][T][128] -> [B][H][128][T] -------
__global__ __launch_bounds__(256)
void v_transpose(const ushort_t* __restrict__ v, ushort_t* __restrict__ vt) {
  __shared__ __align__(16) ushort_t L[64][136];
  int bh = blockIdx.y;
  int t0 = blockIdx.x * 64;
  int tid = threadIdx.x;
  int row = tid >> 2, c0 = (tid & 3) * 32;
  const ushort_t* src = v + ((size_t)bh * T_SEQ + t0 + row) * HD + c0;
#pragma unroll
  for (int j = 0; j < 4; ++j)
    *(short8*)&L[row][c0 + j * 8] = *(const short8*)(src + j * 8);
  __syncthreads();
  int d = tid >> 1, tc = (tid & 1) * 32;
  union { ushort_t u[32]; short8 v8[4]; } buf;
#pragma unroll
  for (int j = 0; j < 32; ++j) buf.u[j] = L[tc + j][d];
  ushort_t* dst = vt + ((size_t)bh * HD + d) * T_SEQ + t0 + tc;
#pragma unroll
  for (int j = 0; j < 4; ++j) *(short8*)(dst + j * 8) = buf.v8[j];
}

// ===== 256x128 BK=32 double-buffered GEMM, 2 blocks/CU (m97 regime) ===
// C = A[M][K] * Bt[N][K]^T. 512 thr = 8 waves (4M x 2N), per-wave 64x64.
// Per K-tile: {stage(kt+1 -> buf^1): 3 gload16 | 8 ds_read_b128 | 16 MFMA
// (setprio) | __syncthreads (auto vmcnt0+lgkm0 drain)}. ONE barrier/K-tile;
// cross-block wave overlap (2 blocks/CU via 48KB LDS + <=128 VGPR) hides
// the drain (m114). LDS swizzle: chunk ^= (row&3)^((row>>2)&3)  (2-way=free),
// applied on pre-swizzled global source AND the ds_read address.
// EPI=0: C fp32. EPI=1: q,k rope-fused scatter; v plain scatter.
template <int EPI>
__global__ __launch_bounds__(512, 4)
void gemm_s(const ushort_t* __restrict__ A, const ushort_t* __restrict__ Bt,
            float* __restrict__ C, ushort_t* __restrict__ q_t,
            ushort_t* __restrict__ k_t, ushort_t* __restrict__ v_t,
            const float* __restrict__ trig, int M, int N, int K) {
  __shared__ __align__(16) ushort_t sA[2][256 * 32];  // 2 x 16KB
  __shared__ __align__(16) ushort_t sB[2][128 * 32];  // 2 x 8KB
  int tid = threadIdx.x, lane = tid & 63, w = tid >> 6;
  int wm = w >> 1, wn = w & 1;
  int li = lane & 15, lg = lane >> 4;
  int tile_m = blockIdx.y * 256, tile_n = blockIdx.x * 128;
  const ushort_t* Ag = A + (size_t)tile_m * K;
  const ushort_t* Bg = Bt + (size_t)tile_n * K;

  int srow = tid >> 2;            // 0..127
  int sc0  = tid & 3;             // linear chunk slot

  auto swz = [](int r, int c) { return c ^ (r & 3) ^ ((r >> 2) & 3); };

  auto stage = [&](int kt, int buf) {
#pragma unroll
    for (int i = 0; i < 2; ++i) {  // A: two 128-row passes
      int row = i * 128 + srow;
      gload16(Ag + (size_t)row * K + kt * 32 + swz(row, sc0) * 8,
              &sA[buf][i * 4096 + tid * 8]);
    }
    gload16(Bg + (size_t)srow * K + kt * 32 + swz(srow, sc0) * 8,
            &sB[buf][tid * 8]);
  };

  f32x4 acc[4][4] = {};
  const int NT = K / 32;

  stage(0, 0);
  __syncthreads();

  for (int kt = 0; kt < NT; ++kt) {
    int cur = kt & 1;
    if (kt + 1 < NT) stage(kt + 1, cur ^ 1);
    short8 af[4], bf[4];
#pragma unroll
    for (int mi = 0; mi < 4; ++mi) {
      int row = wm * 64 + mi * 16 + li;
      af[mi] = *(const short8*)&sA[cur][row * 32 + swz(row, lg) * 8];
    }
#pragma unroll
    for (int ni = 0; ni < 4; ++ni) {
      int row = wn * 64 + ni * 16 + li;
      bf[ni] = *(const short8*)&sB[cur][row * 32 + swz(row, lg) * 8];
    }
    __builtin_amdgcn_s_setprio(1);
#pragma unroll
    for (int mi = 0; mi < 4; ++mi)
#pragma unroll
      for (int ni = 0; ni < 4; ++ni)
        acc[mi][ni] = __builtin_amdgcn_mfma_f32_16x16x32_bf16(af[mi], bf[ni], acc[mi][ni], 0, 0, 0);
    __builtin_amdgcn_s_setprio(0);
    __syncthreads();   // drains vmcnt(0)+lgkmcnt(0): buf^1 writes landed
  }

  if (EPI == 0) {
#pragma unroll
    for (int mi = 0; mi < 4; ++mi) {
      int trow = tile_m + wm * 64 + mi * 16 + lg * 4;
#pragma unroll
      for (int ni = 0; ni < 4; ++ni) {
        int col = tile_n + wn * 64 + ni * 16 + li;
#pragma unroll
        for (int r = 0; r < 4; ++r)
          C[(size_t)(trow + r) * N + col] = acc[mi][ni][r];
      }
    }
  } else {
    int sec = tile_n >> 11;          // block-uniform (128-wide tile, one head)
    int bq  = tile_m >> 11;
    int t0  = tile_m & 2047;
    int h   = (tile_n & 2047) >> 7;
#pragma unroll
    for (int mi = 0; mi < 4; ++mi) {
      int tl = wm * 64 + mi * 16 + lg * 4;
#pragma unroll
      for (int ni = 0; ni < 4; ++ni) {
        int d = wn * 64 + ni * 16 + li;
        if (sec < 2) {
          ushort_t* base = ((sec == 0) ? q_t : k_t) + ((size_t)(bq * NH + h)) * T_SEQ * HD;
          int fi2 = (d >> 1) * 2;
#pragma unroll
          for (int r = 0; r < 4; ++r) {
            int t = t0 + tl + r;
            float val = acc[mi][ni][r];
            float par = __shfl_xor(val, 1);
            const float* tp = trig + t * 128 + fi2;
            float c = tp[0], s = tp[1];
            float outv = (li & 1) ? (par * s + val * c) : (val * c - par * s);
            base[(size_t)t * HD + d] = f2bf(outv);
          }
        } else {
          ushort_t* base = v_t + ((size_t)(bq * NH + h)) * T_SEQ * HD;
#pragma unroll
          for (int r = 0; r < 4; ++r)
            base[(size_t)(t0 + tl + r) * HD + d] = f2bf(acc[mi][ni][r]);
        }
      }
    }
  }
}

// ---------------- Flash attention (causal), swapped-QK 32x32 ----------
__global__ __launch_bounds__(256, 2)
void flash_attn(const ushort_t* __restrict__ Q, const ushort_t* __restrict__ Kg,
                const ushort_t* __restrict__ Vt, ushort_t* __restrict__ Y) {
  __shared__ __align__(16) ushort_t ldsK[2 * 64 * 128];   // 32KB, 2 buf
  __shared__ __align__(16) ushort_t ldsV[2 * 128 * 64];   // 32KB, 2 buf
  int tid = threadIdx.x, lane = tid & 63, w = tid >> 6;
  int hi = lane >> 5, l31 = lane & 31;
  int qi = (blockIdx.y & 16) ? (15 - (int)blockIdx.x) : (int)blockIdx.x;
  int bh = blockIdx.y;
  int b = bh >> 4, h = bh & 15;
  int q0 = qi * 128;
  const ushort_t* Qp = Q + (size_t)bh * T_SEQ * HD;
  const ushort_t* Kp = Kg + (size_t)bh * T_SEQ * HD;
  const ushort_t* Vp = Vt + (size_t)bh * HD * T_SEQ;

  int qg = q0 + w * 32 + l31;
  int qmaxw = q0 + w * 32 + 31;

  auto stage = [&](int kv0, int bsel) {
    ushort_t* Kb = ldsK + bsel * 8192;
    ushort_t* Vb = ldsV + bsel * 8192;
#pragma unroll
    for (int p = 0; p < 4; ++p) {
      int c = p * 256 + w * 64 + lane;
      {
        int row = c >> 4, cc = c & 15;
        int sc = cc ^ (row & 15);
        gload16(Kp + (size_t)(kv0 + row) * HD + sc * 8, Kb + (p * 256 + w * 64) * 8);
      }
      {
        int d = c >> 3, cc = c & 7;
        int sc = cc ^ (d & 7);
        gload16(Vp + (size_t)d * T_SEQ + kv0 + sc * 8, Vb + (p * 256 + w * 64) * 8);
      }
    }
  };

  short8 qf[8];
#pragma unroll
  for (int ds = 0; ds < 8; ++ds)
    qf[ds] = *(const short8*)(Qp + (size_t)qg * HD + ds * 16 + hi * 8);

  f32x16 o[4] = {};
  float mu = -1e30f, l = 0.f;
  const float SIG = 0.12751879523209784f;  // (1/sqrt(128)) * log2(e)

  int nkt = 2 * qi + 2;
  stage(0, 0);
  __syncthreads();
  int cur = 0;
  for (int kt = 0; kt < nkt; ++kt) {
    int kv0 = kt * 64;
    if (kt + 1 < nkt) stage((kt + 1) * 64, cur ^ 1);
    if (kv0 <= qmaxw) {
      const ushort_t* Kb = ldsK + cur * 8192;
      const ushort_t* Vb = ldsV + cur * 8192;
      f32x16 sa = {}, sb = {};
      __builtin_amdgcn_s_setprio(1);
#pragma unroll
      for (int ds = 0; ds < 8; ++ds) {
        int cc = ds * 2 + hi;
        short8 k0 = *(const short8*)&Kb[l31 * 128 + ((cc ^ (l31 & 15)) * 8)];
        short8 k1 = *(const short8*)&Kb[(32 + l31) * 128 + ((cc ^ (l31 & 15)) * 8)];
        sa = __builtin_amdgcn_mfma_f32_32x32x16_bf16(k0, qf[ds], sa, 0, 0, 0);
        sb = __builtin_amdgcn_mfma_f32_32x32x16_bf16(k1, qf[ds], sb, 0, 0, 0);
      }
      __builtin_amdgcn_s_setprio(0);
      float p[32];
#pragma unroll
      for (int r = 0; r < 16; ++r) { p[r] = sa[r] * SIG; p[16 + r] = sb[r] * SIG; }
      if (kv0 + 63 > q0 + w * 32) {
#pragma unroll
        for (int r = 0; r < 16; ++r) {
          int loc = (r & 3) + 8 * (r >> 2) + 4 * hi;
          if (kv0 + loc > qg)      p[r]      = -3e38f;
          if (kv0 + 32 + loc > qg) p[16 + r] = -3e38f;
        }
      }
      float tm[16];
#pragma unroll
      for (int i = 0; i < 16; ++i) tm[i] = fmaxf(p[i], p[i + 16]);
#pragma unroll
      for (int st = 8; st >= 1; st >>= 1)
#pragma unroll
        for (int i = 0; i < 8; ++i)
          if (i < st) tm[i] = fmaxf(tm[i], tm[i + st]);
      float pmax = fmaxf(tm[0], __shfl_xor(tm[0], 32));
      bool resc = !__all(pmax <= mu + 11.0f);
      if (resc) {
        float munew = fmaxf(mu, pmax);
        float alpha = fexp2(mu - munew);
        mu = munew;
        l *= alpha;
#pragma unroll
        for (int dsub = 0; dsub < 4; ++dsub)
#pragma unroll
          for (int r = 0; r < 16; ++r) o[dsub][r] *= alpha;
      }
#pragma unroll
      for (int i = 0; i < 32; ++i) p[i] = fexp2(p[i] - mu);
      float ts[16];
#pragma unroll
      for (int i = 0; i < 16; ++i) ts[i] = p[i] + p[i + 16];
#pragma unroll
      for (int st = 8; st >= 1; st >>= 1)
#pragma unroll
        for (int i = 0; i < 8; ++i)
          if (i < st) ts[i] += ts[i + st];
      l += ts[0] + __shfl_xor(ts[0], 32);
      __builtin_amdgcn_s_setprio(1);
#pragma unroll
      for (int s = 0; s < 4; ++s) {
        int rb = (s >> 1) * 16 + (s & 1) * 8;
        unsigned a0 = pk2(p[rb + 0], p[rb + 1]);
        unsigned a1 = pk2(p[rb + 2], p[rb + 3]);
        unsigned a2 = pk2(p[rb + 4], p[rb + 5]);
        unsigned a3 = pk2(p[rb + 6], p[rb + 7]);
        unsigned sa0 = (unsigned)__shfl_xor((int)a0, 32);
        unsigned sa1 = (unsigned)__shfl_xor((int)a1, 32);
        unsigned sa2 = (unsigned)__shfl_xor((int)a2, 32);
        unsigned sa3 = (unsigned)__shfl_xor((int)a3, 32);
        union { unsigned u[4]; short8 s8; } pf;
        pf.u[0] = hi ? sa2 : a0;
        pf.u[1] = hi ? sa3 : a1;
        pf.u[2] = hi ? a2 : sa0;
        pf.u[3] = hi ? a3 : sa1;
#pragma unroll
        for (int dsub = 0; dsub < 4; ++dsub) {
          int row = dsub * 32 + l31;
          short8 vf = *(const short8*)&Vb[row * 64 + (((2 * s + hi) ^ (row & 7)) * 8)];
          o[dsub] = __builtin_amdgcn_mfma_f32_32x32x16_bf16(vf, pf.s8, o[dsub], 0, 0, 0);
        }
      }
      __builtin_amdgcn_s_setprio(0);
    }
    __syncthreads();
    cur ^= 1;
  }
  float invl = 1.f / l;
#pragma unroll
  for (int dsub = 0; dsub < 4; ++dsub)
#pragma unroll
    for (int r = 0; r < 16; ++r) o[dsub][r] *= invl;
#pragma unroll
  for (int dsub = 0; dsub < 4; ++dsub)
#pragma unroll
    for (int r = 0; r < 16; r += 2) {
      int d0 = dsub * 32 + (r & 3) + 8 * (r >> 2) + 4 * hi;
      unsigned u = pk2(o[dsub][r], o[dsub][r + 1]);
      *(unsigned*)&ldsK[w * 4096 + l31 * 128 + (((d0 >> 3) ^ (l31 & 15)) * 8) + (d0 & 7)] = u;
    }
  __syncthreads();
#pragma unroll
  for (int rep = 0; rep < 8; ++rep) {
    int idx = rep * 256 + tid;
    int qg2 = idx >> 4, c = idx & 15;
    int wv2 = qg2 >> 5, ql = qg2 & 31;
    short8 val = *(const short8*)&ldsK[wv2 * 4096 + ql * 128 + ((c ^ (ql & 15)) * 8)];
    *(short8*)(Y + ((size_t)(b * T_SEQ + q0 + qg2)) * DMODEL + h * HD + c * 8) = val;
  }
}

extern "C" void kernel_launch(void* const* d_in, const int* in_sizes, int n_in,
                              void* d_out, int out_size, void* d_ws, size_t ws_size,
                              hipStream_t stream) {
  const float* x      = (const float*)d_in[0];
  const float* w_attn = (const float*)d_in[1];
  const float* w_proj = (const float*)d_in[2];
  float* out = (float*)d_out;

  char* ws = (char*)d_ws;
  size_t off = 0;
  auto alloc = [&](size_t bytes) -> void* {
    void* p = ws + off;
    off = (off + bytes + 255) & ~(size_t)255;
    return p;
  };
  const size_t MT = (size_t)NB * T_SEQ;          // 4096
  ushort_t* xb   = (ushort_t*)alloc(MT * DMODEL * 2);
  ushort_t* wab  = (ushort_t*)alloc((size_t)3 * DMODEL * DMODEL * 2);
  ushort_t* wpb  = (ushort_t*)alloc((size_t)DMODEL * DMODEL * 2);
  ushort_t* q_t  = (ushort_t*)alloc(MT * DMODEL * 2);
  ushort_t* k_t  = (ushort_t*)alloc(MT * DMODEL * 2);
  ushort_t* v_t  = (ushort_t*)alloc(MT * DMODEL * 2);
  ushort_t* vtb  = (ushort_t*)alloc(MT * DMODEL * 2);
  ushort_t* yb   = (ushort_t*)alloc(MT * DMODEL * 2);
  float*    trig = (float*)alloc((size_t)T_SEQ * 64 * 2 * 4);
  (void)ws_size; (void)n_in; (void)in_sizes; (void)out_size;

  {  // converts
    int n8x = (int)(MT * DMODEL / 8);
    hipLaunchKernelGGL(cvt_f32_bf16, dim3((n8x + 255) / 256), dim3(256), 0, stream, x, xb, n8x);
    int n8a = (int)((size_t)3 * DMODEL * DMODEL / 8);
    hipLaunchKernelGGL(cvt_f32_bf16, dim3((n8a + 255) / 256), dim3(256), 0, stream, w_attn, wab, n8a);
    int n8p = (int)((size_t)DMODEL * DMODEL / 8);
    hipLaunchKernelGGL(cvt_f32_bf16, dim3((n8p + 255) / 256), dim3(256), 0, stream, w_proj, wpb, n8p);
  }
  hipLaunchKernelGGL(trig_init, dim3(T_SEQ * 64 / 256), dim3(256), 0, stream, trig);

  // QKV projection (256x128, 2 blocks/CU), rope fused q/k, plain v scatter
  hipLaunchKernelGGL((gemm_s<1>), dim3(3 * DMODEL / 128, MT / 256), dim3(512), 0, stream,
                     xb, wab, (float*)nullptr, q_t, k_t, v_t, trig,
                     (int)MT, 3 * DMODEL, DMODEL);

  hipLaunchKernelGGL(v_transpose, dim3(T_SEQ / 64, NB * NH), dim3(256), 0, stream, v_t, vtb);

  hipLaunchKernelGGL(flash_attn, dim3(T_SEQ / 128, NB * NH), dim3(256), 0, stream,
                     q_t, k_t, vtb, yb);

  // output projection
  hipLaunchKernelGGL((gemm_s<0>), dim3(DMODEL / 128, MT / 256), dim3(512), 0, stream,
                     yb, wpb, out, (ushort_t*)nullptr, (ushort_t*)nullptr, (ushort_t*)nullptr,
                     (const float*)nullptr, (int)MT, DMODEL, DMODEL);
}

// Round 9
// 292.822 us; speedup vs baseline: 1.1168x; 1.0586x over previous
//
#include <hip/hip_runtime.h>
#include <hip/hip_bf16.h>

#define T_SEQ 2048
#define DMODEL 2048
#define NB 2
#define NH 16
#define HD 128

typedef __attribute__((ext_vector_type(8))) short short8;
typedef __attribute__((ext_vector_type(4))) float f32x4;
typedef __attribute__((ext_vector_type(16))) float f32x16;
typedef unsigned short ushort_t;

__device__ inline ushort_t f2bf(float f) {
  union { float f; unsigned u; } v; v.f = f;
  unsigned r = v.u + 0x7fffu + ((v.u >> 16) & 1u);
  return (ushort_t)(r >> 16);
}
__device__ inline float bf2f(ushort_t u) {
  union { unsigned u; float f; } v; v.u = ((unsigned)u) << 16;
  return v.f;
}
__device__ inline unsigned pk2(float x, float y) {
  union { __hip_bfloat162 h; unsigned u; } c;
  c.h = __float22bfloat162_rn(float2{x, y});
  return c.u;
}
__device__ inline float fexp2(float x) {
  float r;
  asm("v_exp_f32 %0, %1" : "=v"(r) : "v"(x));
  return r;
}

__device__ inline void gload16(const void* g, void* l) {
  __builtin_amdgcn_global_load_lds(
      (const __attribute__((address_space(1))) unsigned*)g,
      (__attribute__((address_space(3))) unsigned*)l, 16, 0, 0);
}

// ---------------- fp32 -> bf16 convert, 8 elems/thread ----------------
__global__ void cvt_f32_bf16(const float* __restrict__ src, ushort_t* __restrict__ dst, int n8) {
  int i = blockIdx.x * blockDim.x + threadIdx.x;
  if (i >= n8) return;
  const float4* s = (const float4*)src + (size_t)i * 2;
  float4 a = s[0], b = s[1];
  short8 o;
  o[0] = (short)f2bf(a.x); o[1] = (short)f2bf(a.y);
  o[2] = (short)f2bf(a.z); o[3] = (short)f2bf(a.w);
  o[4] = (short)f2bf(b.x); o[5] = (short)f2bf(b.y);
  o[6] = (short)f2bf(b.z); o[7] = (short)f2bf(b.w);
  *((short8*)dst + i) = o;
}

// ---------------- cos/sin table: trig[t*128 + i*2]=cos, +1=sin --------
__global__ void trig_init(float* __restrict__ trig) {
  int idx = blockIdx.x * blockDim.x + threadIdx.x;  // T*64
  if (idx >= T_SEQ * 64) return;
  int i = idx & 63, t = idx >> 6;
  float inv = __expf(-(float)i * (9.210340371976184f / 64.0f));
  float f = (float)t * inv;
  trig[idx * 2]     = cosf(f);
  trig[idx * 2 + 1] = sinf(f);
}

// ---------------- V transpose: [B][H][T][128] -> [B][H][128][T] -------
__global__ __launch_bounds__(256)
void v_transpose(const ushort_t* __restrict__ v, ushort_t* __restrict__ vt) {
  __shared__ __align__(16) ushort_t L[64][136];
  int bh = blockIdx.y;
  int t0 = blockIdx.x * 64;
  int tid = threadIdx.x;
  int row = tid >> 2, c0 = (tid & 3) * 32;
  const ushort_t* src = v + ((size_t)bh * T_SEQ + t0 + row) * HD + c0;
#pragma unroll
  for (int j = 0; j < 4; ++j)
    *(short8*)&L[row][c0 + j * 8] = *(const short8*)(src + j * 8);
  __syncthreads();
  int d = tid >> 1, tc = (tid & 1) * 32;
  union { ushort_t u[32]; short8 v8[4]; } buf;
#pragma unroll
  for (int j = 0; j < 32; ++j) buf.u[j] = L[tc + j][d];
  ushort_t* dst = vt + ((size_t)bh * HD + d) * T_SEQ + t0 + tc;
#pragma unroll
  for (int j = 0; j < 4; ++j) *(short8*)(dst + j * 8) = buf.v8[j];
}

// ===== 256x128 BK=32 double-buffered GEMM, m97 regime, 0-conflict =====
// C = A[M][K] * Bt[N][K]^T. 512 thr = 8 waves (4M x 2N), per-wave 64x64.
// Per K-tile: {stage(kt+1 -> buf^1): 3 gload16 | 8 ds_read_b128 | 16 MFMA
// (setprio) | __syncthreads (auto vmcnt0+lgkm0 drain)}. ONE barrier/K-tile.
// LDS layout (BK=32 rows are 64B -> bank depends on row PARITY): pack row
// pairs into 128B super-rows of 8 x 16B slots; row r chunk g lives at slot
// s = (((r&1)<<2)|g) ^ ((r>>1)&7).  Read (16 lanes, fixed g): slot =
// ((li&1)<<2|g)^(li>>1) -> every 8-lane group covers all 32 banks (0 extra
// passes).  Stage keeps linear gload_lds dest; source decodes (p,g) =
// slot ^ (R&7) per lane (involutive XOR, rule both-sides-or-neither).
template <int EPI>
__global__ __launch_bounds__(512, 4)
void gemm_s(const ushort_t* __restrict__ A, const ushort_t* __restrict__ Bt,
            float* __restrict__ C, ushort_t* __restrict__ q_t,
            ushort_t* __restrict__ k_t, ushort_t* __restrict__ v_t,
            const float* __restrict__ trig, int M, int N, int K) {
  __shared__ __align__(16) ushort_t sA[2][256 * 32];  // 2 x 16KB
  __shared__ __align__(16) ushort_t sB[2][128 * 32];  // 2 x 8KB
  int tid = threadIdx.x, lane = tid & 63, w = tid >> 6;
  int wm = w >> 1, wn = w & 1;
  int li = lane & 15, lg = lane >> 4;
  int tile_m = blockIdx.y * 256, tile_n = blockIdx.x * 128;
  const ushort_t* Ag = A + (size_t)tile_m * K;
  const ushort_t* Bg = Bt + (size_t)tile_n * K;

  // stage decode: lane's LDS slot (linear) -> global (row, chunk)
  int Rl = tid >> 3;           // superrow within instruction's 64-superrow span
  int sl = tid & 7;            // slot
  int tdec = sl ^ (Rl & 7);
  int prow = (tdec >> 2) & 1, gch = tdec & 3;

  auto stage = [&](int kt, int buf) {
#pragma unroll
    for (int i = 0; i < 2; ++i) {  // A: 2 instrs x 64 superrows (128 rows)
      int grow = (i * 64 + Rl) * 2 + prow;
      gload16(Ag + (size_t)grow * K + kt * 32 + gch * 8,
              &sA[buf][i * 4096 + tid * 8]);
    }
    {                              // B: 1 instr x 64 superrows (128 rows)
      int grow = Rl * 2 + prow;
      gload16(Bg + (size_t)grow * K + kt * 32 + gch * 8,
              &sB[buf][tid * 8]);
    }
  };

  // read addressing: row r, global chunk lg -> element R*64 + slot*8
  auto rdoff = [&](int r) {
    int R = r >> 1;
    int s = (((r & 1) << 2) | lg) ^ (R & 7);
    return R * 64 + s * 8;
  };

  f32x4 acc[4][4] = {};
  const int NT = K / 32;

  stage(0, 0);
  __syncthreads();

  for (int kt = 0; kt < NT; ++kt) {
    int cur = kt & 1;
    if (kt + 1 < NT) stage(kt + 1, cur ^ 1);
    short8 af[4], bf[4];
#pragma unroll
    for (int mi = 0; mi < 4; ++mi)
      af[mi] = *(const short8*)&sA[cur][rdoff(wm * 64 + mi * 16 + li)];
#pragma unroll
    for (int ni = 0; ni < 4; ++ni)
      bf[ni] = *(const short8*)&sB[cur][rdoff(wn * 64 + ni * 16 + li)];
    __builtin_amdgcn_s_setprio(1);
#pragma unroll
    for (int mi = 0; mi < 4; ++mi)
#pragma unroll
      for (int ni = 0; ni < 4; ++ni)
        acc[mi][ni] = __builtin_amdgcn_mfma_f32_16x16x32_bf16(af[mi], bf[ni], acc[mi][ni], 0, 0, 0);
    __builtin_amdgcn_s_setprio(0);
    __syncthreads();   // drains vmcnt(0)+lgkmcnt(0): buf^1 writes landed
  }

  if (EPI == 0) {
#pragma unroll
    for (int mi = 0; mi < 4; ++mi) {
      int trow = tile_m + wm * 64 + mi * 16 + lg * 4;
#pragma unroll
      for (int ni = 0; ni < 4; ++ni) {
        int col = tile_n + wn * 64 + ni * 16 + li;
#pragma unroll
        for (int r = 0; r < 4; ++r)
          C[(size_t)(trow + r) * N + col] = acc[mi][ni][r];
      }
    }
  } else {
    int sec = tile_n >> 11;          // block-uniform (128-wide tile, one head)
    int bq  = tile_m >> 11;
    int t0  = tile_m & 2047;
    int h   = (tile_n & 2047) >> 7;
#pragma unroll
    for (int mi = 0; mi < 4; ++mi) {
      int tl = wm * 64 + mi * 16 + lg * 4;
#pragma unroll
      for (int ni = 0; ni < 4; ++ni) {
        int d = wn * 64 + ni * 16 + li;
        if (sec < 2) {
          ushort_t* base = ((sec == 0) ? q_t : k_t) + ((size_t)(bq * NH + h)) * T_SEQ * HD;
          int fi2 = (d >> 1) * 2;
#pragma unroll
          for (int r = 0; r < 4; ++r) {
            int t = t0 + tl + r;
            float val = acc[mi][ni][r];
            float par = __shfl_xor(val, 1);
            const float* tp = trig + t * 128 + fi2;
            float c = tp[0], s = tp[1];
            float outv = (li & 1) ? (par * s + val * c) : (val * c - par * s);
            base[(size_t)t * HD + d] = f2bf(outv);
          }
        } else {
          ushort_t* base = v_t + ((size_t)(bq * NH + h)) * T_SEQ * HD;
#pragma unroll
          for (int r = 0; r < 4; ++r)
            base[(size_t)(t0 + tl + r) * HD + d] = f2bf(acc[mi][ni][r]);
        }
      }
    }
  }
}

// ---------------- Flash attention (causal), swapped-QK 32x32 ----------
__global__ __launch_bounds__(256, 2)
void flash_attn(const ushort_t* __restrict__ Q, const ushort_t* __restrict__ Kg,
                const ushort_t* __restrict__ Vt, ushort_t* __restrict__ Y) {
  __shared__ __align__(16) ushort_t ldsK[2 * 64 * 128];   // 32KB, 2 buf
  __shared__ __align__(16) ushort_t ldsV[2 * 128 * 64];   // 32KB, 2 buf
  int tid = threadIdx.x, lane = tid & 63, w = tid >> 6;
  int hi = lane >> 5, l31 = lane & 31;
  int qi = (blockIdx.y & 16) ? (15 - (int)blockIdx.x) : (int)blockIdx.x;
  int bh = blockIdx.y;
  int b = bh >> 4, h = bh & 15;
  int q0 = qi * 128;
  const ushort_t* Qp = Q + (size_t)bh * T_SEQ * HD;
  const ushort_t* Kp = Kg + (size_t)bh * T_SEQ * HD;
  const ushort_t* Vp = Vt + (size_t)bh * HD * T_SEQ;

  int qg = q0 + w * 32 + l31;
  int qmaxw = q0 + w * 32 + 31;

  auto stage = [&](int kv0, int bsel) {
    ushort_t* Kb = ldsK + bsel * 8192;
    ushort_t* Vb = ldsV + bsel * 8192;
#pragma unroll
    for (int p = 0; p < 4; ++p) {
      int c = p * 256 + w * 64 + lane;
      {
        int row = c >> 4, cc = c & 15;
        int sc = cc ^ (row & 15);
        gload16(Kp + (size_t)(kv0 + row) * HD + sc * 8, Kb + (p * 256 + w * 64) * 8);
      }
      {
        int d = c >> 3, cc = c & 7;
        int sc = cc ^ (d & 7);
        gload16(Vp + (size_t)d * T_SEQ + kv0 + sc * 8, Vb + (p * 256 + w * 64) * 8);
      }
    }
  };

  short8 qf[8];
#pragma unroll
  for (int ds = 0; ds < 8; ++ds)
    qf[ds] = *(const short8*)(Qp + (size_t)qg * HD + ds * 16 + hi * 8);

  f32x16 o[4] = {};
  float mu = -1e30f, l = 0.f;
  const float SIG = 0.12751879523209784f;  // (1/sqrt(128)) * log2(e)

  int nkt = 2 * qi + 2;
  stage(0, 0);
  __syncthreads();
  int cur = 0;
  for (int kt = 0; kt < nkt; ++kt) {
    int kv0 = kt * 64;
    if (kt + 1 < nkt) stage((kt + 1) * 64, cur ^ 1);
    if (kv0 <= qmaxw) {
      const ushort_t* Kb = ldsK + cur * 8192;
      const ushort_t* Vb = ldsV + cur * 8192;
      f32x16 sa = {}, sb = {};
      __builtin_amdgcn_s_setprio(1);
#pragma unroll
      for (int ds = 0; ds < 8; ++ds) {
        int cc = ds * 2 + hi;
        short8 k0 = *(const short8*)&Kb[l31 * 128 + ((cc ^ (l31 & 15)) * 8)];
        short8 k1 = *(const short8*)&Kb[(32 + l31) * 128 + ((cc ^ (l31 & 15)) * 8)];
        sa = __builtin_amdgcn_mfma_f32_32x32x16_bf16(k0, qf[ds], sa, 0, 0, 0);
        sb = __builtin_amdgcn_mfma_f32_32x32x16_bf16(k1, qf[ds], sb, 0, 0, 0);
      }
      __builtin_amdgcn_s_setprio(0);
      float p[32];
#pragma unroll
      for (int r = 0; r < 16; ++r) { p[r] = sa[r] * SIG; p[16 + r] = sb[r] * SIG; }
      if (kv0 + 63 > q0 + w * 32) {
#pragma unroll
        for (int r = 0; r < 16; ++r) {
          int loc = (r & 3) + 8 * (r >> 2) + 4 * hi;
          if (kv0 + loc > qg)      p[r]      = -3e38f;
          if (kv0 + 32 + loc > qg) p[16 + r] = -3e38f;
        }
      }
      float tm[16];
#pragma unroll
      for (int i = 0; i < 16; ++i) tm[i] = fmaxf(p[i], p[i + 16]);
#pragma unroll
      for (int st = 8; st >= 1; st >>= 1)
#pragma unroll
        for (int i = 0; i < 8; ++i)
          if (i < st) tm[i] = fmaxf(tm[i], tm[i + st]);
      float pmax = fmaxf(tm[0], __shfl_xor(tm[0], 32));
      bool resc = !__all(pmax <= mu + 11.0f);
      if (resc) {
        float munew = fmaxf(mu, pmax);
        float alpha = fexp2(mu - munew);
        mu = munew;
        l *= alpha;
#pragma unroll
        for (int dsub = 0; dsub < 4; ++dsub)
#pragma unroll
          for (int r = 0; r < 16; ++r) o[dsub][r] *= alpha;
      }
#pragma unroll
      for (int i = 0; i < 32; ++i) p[i] = fexp2(p[i] - mu);
      float ts[16];
#pragma unroll
      for (int i = 0; i < 16; ++i) ts[i] = p[i] + p[i + 16];
#pragma unroll
      for (int st = 8; st >= 1; st >>= 1)
#pragma unroll
        for (int i = 0; i < 8; ++i)
          if (i < st) ts[i] += ts[i + st];
      l += ts[0] + __shfl_xor(ts[0], 32);
      __builtin_amdgcn_s_setprio(1);
#pragma unroll
      for (int s = 0; s < 4; ++s) {
        int rb = (s >> 1) * 16 + (s & 1) * 8;
        unsigned a0 = pk2(p[rb + 0], p[rb + 1]);
        unsigned a1 = pk2(p[rb + 2], p[rb + 3]);
        unsigned a2 = pk2(p[rb + 4], p[rb + 5]);
        unsigned a3 = pk2(p[rb + 6], p[rb + 7]);
        unsigned sa0 = (unsigned)__shfl_xor((int)a0, 32);
        unsigned sa1 = (unsigned)__shfl_xor((int)a1, 32);
        unsigned sa2 = (unsigned)__shfl_xor((int)a2, 32);
        unsigned sa3 = (unsigned)__shfl_xor((int)a3, 32);
        union { unsigned u[4]; short8 s8; } pf;
        pf.u[0] = hi ? sa2 : a0;
        pf.u[1] = hi ? sa3 : a1;
        pf.u[2] = hi ? a2 : sa0;
        pf.u[3] = hi ? a3 : sa1;
#pragma unroll
        for (int dsub = 0; dsub < 4; ++dsub) {
          int row = dsub * 32 + l31;
          short8 vf = *(const short8*)&Vb[row * 64 + (((2 * s + hi) ^ (row & 7)) * 8)];
          o[dsub] = __builtin_amdgcn_mfma_f32_32x32x16_bf16(vf, pf.s8, o[dsub], 0, 0, 0);
        }
      }
      __builtin_amdgcn_s_setprio(0);
    }
    __syncthreads();
    cur ^= 1;
  }
  float invl = 1.f / l;
#pragma unroll
  for (int dsub = 0; dsub < 4; ++dsub)
#pragma unroll
    for (int r = 0; r < 16; ++r) o[dsub][r] *= invl;
#pragma unroll
  for (int dsub = 0; dsub < 4; ++dsub)
#pragma unroll
    for (int r = 0; r < 16; r += 2) {
      int d0 = dsub * 32 + (r & 3) + 8 * (r >> 2) + 4 * hi;
      unsigned u = pk2(o[dsub][r], o[dsub][r + 1]);
      *(unsigned*)&ldsK[w * 4096 + l31 * 128 + (((d0 >> 3) ^ (l31 & 15)) * 8) + (d0 & 7)] = u;
    }
  __syncthreads();
#pragma unroll
  for (int rep = 0; rep < 8; ++rep) {
    int idx = rep * 256 + tid;
    int qg2 = idx >> 4, c = idx & 15;
    int wv2 = qg2 >> 5, ql = qg2 & 31;
    short8 val = *(const short8*)&ldsK[wv2 * 4096 + ql * 128 + ((c ^ (ql & 15)) * 8)];
    *(short8*)(Y + ((size_t)(b * T_SEQ + q0 + qg2)) * DMODEL + h * HD + c * 8) = val;
  }
}

extern "C" void kernel_launch(void* const* d_in, const int* in_sizes, int n_in,
                              void* d_out, int out_size, void* d_ws, size_t ws_size,
                              hipStream_t stream) {
  const float* x      = (const float*)d_in[0];
  const float* w_attn = (const float*)d_in[1];
  const float* w_proj = (const float*)d_in[2];
  float* out = (float*)d_out;

  char* ws = (char*)d_ws;
  size_t off = 0;
  auto alloc = [&](size_t bytes) -> void* {
    void* p = ws + off;
    off = (off + bytes + 255) & ~(size_t)255;
    return p;
  };
  const size_t MT = (size_t)NB * T_SEQ;          // 4096
  ushort_t* xb   = (ushort_t*)alloc(MT * DMODEL * 2);
  ushort_t* wab  = (ushort_t*)alloc((size_t)3 * DMODEL * DMODEL * 2);
  ushort_t* wpb  = (ushort_t*)alloc((size_t)DMODEL * DMODEL * 2);
  ushort_t* q_t  = (ushort_t*)alloc(MT * DMODEL * 2);
  ushort_t* k_t  = (ushort_t*)alloc(MT * DMODEL * 2);
  ushort_t* v_t  = (ushort_t*)alloc(MT * DMODEL * 2);
  ushort_t* vtb  = (ushort_t*)alloc(MT * DMODEL * 2);
  ushort_t* yb   = (ushort_t*)alloc(MT * DMODEL * 2);
  float*    trig = (float*)alloc((size_t)T_SEQ * 64 * 2 * 4);
  (void)ws_size; (void)n_in; (void)in_sizes; (void)out_size;

  {  // converts
    int n8x = (int)(MT * DMODEL / 8);
    hipLaunchKernelGGL(cvt_f32_bf16, dim3((n8x + 255) / 256), dim3(256), 0, stream, x, xb, n8x);
    int n8a = (int)((size_t)3 * DMODEL * DMODEL / 8);
    hipLaunchKernelGGL(cvt_f32_bf16, dim3((n8a + 255) / 256), dim3(256), 0, stream, w_attn, wab, n8a);
    int n8p = (int)((size_t)DMODEL * DMODEL / 8);
    hipLaunchKernelGGL(cvt_f32_bf16, dim3((n8p + 255) / 256), dim3(256), 0, stream, w_proj, wpb, n8p);
  }
  hipLaunchKernelGGL(trig_init, dim3(T_SEQ * 64 / 256), dim3(256), 0, stream, trig);

  // QKV projection (256x128, conflict-free LDS), rope fused q/k, v scatter
  hipLaunchKernelGGL((gemm_s<1>), dim3(3 * DMODEL / 128, MT / 256), dim3(512), 0, stream,
                     xb, wab, (float*)nullptr, q_t, k_t, v_t, trig,
                     (int)MT, 3 * DMODEL, DMODEL);

  hipLaunchKernelGGL(v_transpose, dim3(T_SEQ / 64, NB * NH), dim3(256), 0, stream, v_t, vtb);

  hipLaunchKernelGGL(flash_attn, dim3(T_SEQ / 128, NB * NH), dim3(256), 0, stream,
                     q_t, k_t, vtb, yb);

  // output projection
  hipLaunchKernelGGL((gemm_s<0>), dim3(DMODEL / 128, MT / 256), dim3(512), 0, stream,
                     yb, wpb, out, (ushort_t*)nullptr, (ushort_t*)nullptr, (ushort_t*)nullptr,
                     (const float*)nullptr, (int)MT, DMODEL, DMODEL);
}